// Round 7
// baseline (120.259 us; speedup 1.0000x reference)
//
#include <hip/hip_runtime.h>

// conv1d: out[b,i] = sum_{k<16,d<512} x[b,i+k,d] * w[k,d] + bias, zero-pad at end.
// R6 = R5 + __launch_bounds__(256,4). R5's only defect was the allocator
// picking 64 VGPRs for a ~115-reg demand -> 86 MB scratch spill (WRITE_SIZE).
// launch_bounds pins the cap at 128 (4 waves/EU == the grid-limited occupancy
// anyway). Structure: block = 256 thr owns a 128-output segment; lane owns
// 2 d's (float2); filter 32 VGPR; 32-slot acc ring (compile-time indices);
// 2-group register prefetch (~1100 cy load->use distance); no barriers or
// branches in the hot path; XCD-contiguous block swizzle.

namespace {
constexpr int S = 4096;
constexpr int D = 512;
constexpr int K = 16;
constexpr int B = 32;
constexpr int SEG = 128;       // outputs per block
constexpr int NCH = SEG / 8;   // 16 chunks of 8 outputs
constexpr int SPR = S / SEG;   // 32 segments per row
constexpr int NBLK = B * SPR;  // 1024 blocks

// FMA one prefetched frame XV into ring slots ((FI - k) & 31); FI,KLO,KHI compile-time
#define FRAME_R(XV, FI, KLO, KHI)              \
  do {                                         \
    _Pragma("unroll")                          \
    for (int k = (KLO); k <= (KHI); ++k) {     \
      const int sl = ((FI) - k) & 31;          \
      acc[sl] = fmaf((XV).x, w[k].x, acc[sl]); \
      acc[sl] = fmaf((XV).y, w[k].y, acc[sl]); \
    }                                          \
  } while (0)

// issue 8 float2 loads of frame-group G into named prefetch regs DST[0..7]
#define PF_GROUP(DST, G)                                      \
  do {                                                        \
    const float* _pp = px + (size_t)(G) * (8 * D);            \
    _Pragma("unroll")                                         \
    for (int f = 0; f < 8; ++f)                               \
      DST[f] = *reinterpret_cast<const float2*>(_pp + f * D); \
  } while (0)

// fold 8 completed ring slots (SB..SB+7, SB compile-time) -> 64-lane sums;
// lane l<8 stores red[C][wv][perm(l)]  (validated in R4/R5)
#define FOLD(SB, C)                                                           \
  do {                                                                        \
    float v[8];                                                               \
    _Pragma("unroll")                                                         \
    for (int i = 0; i < 8; ++i) {                                             \
      const int sl = ((SB) + i) & 31;                                         \
      v[i] = acc[sl];                                                         \
      acc[sl] = 0.f;                                                          \
    }                                                                         \
    const bool f0 = lane & 1, f1 = lane & 2, f2 = lane & 4;                   \
    _Pragma("unroll")                                                         \
    for (int j = 0; j < 4; ++j) {                                             \
      const float sv = f0 ? v[j] : v[j + 4];                                  \
      const float rv = __shfl_xor(sv, 1, 64);                                 \
      v[j] = (f0 ? v[j + 4] : v[j]) + rv;                                     \
    }                                                                         \
    _Pragma("unroll")                                                         \
    for (int j = 0; j < 2; ++j) {                                             \
      const float sv = f1 ? v[j] : v[j + 2];                                  \
      const float rv = __shfl_xor(sv, 2, 64);                                 \
      v[j] = (f1 ? v[j + 2] : v[j]) + rv;                                     \
    }                                                                         \
    {                                                                         \
      const float sv = f2 ? v[0] : v[1];                                      \
      const float rv = __shfl_xor(sv, 4, 64);                                 \
      float tt = (f2 ? v[1] : v[0]) + rv;                                     \
      tt += __shfl_xor(tt, 8, 64);                                            \
      tt += __shfl_xor(tt, 16, 64);                                           \
      tt += __shfl_xor(tt, 32, 64);                                           \
      if (lane < 8)                                                           \
        red[(C)][wv]                                                          \
           [4 * (lane & 1) + 2 * ((lane >> 1) & 1) + ((lane >> 2) & 1)] = tt; \
    }                                                                         \
  } while (0)

__global__ __launch_bounds__(256, 4)
void conv1d_kernel(const float* __restrict__ x,
                   const float* __restrict__ filt,
                   const float* __restrict__ bias,
                   float* __restrict__ out) {
  __shared__ float red[NCH][4][8];  // 2 KB
  const int tid = threadIdx.x;
  const int lane = tid & 63;
  const int wv = tid >> 6;
  const int d0 = wv * 128 + lane * 2;

  // XCD-contiguous swizzle (NBLK % 8 == 0)
  const int bid = blockIdx.x;
  const int lbid = (bid & 7) * (NBLK / 8) + (bid >> 3);
  const int b = lbid >> 5;        // / SPR
  const int seg = lbid & 31;
  const int seg_start = seg * SEG;
  const bool tail = (seg == SPR - 1);  // epilogue frames are zero padding

  float2 w[K];  // 32 VGPR
#pragma unroll
  for (int k = 0; k < K; ++k)
    w[k] = *reinterpret_cast<const float2*>(filt + k * D + d0);

  float acc[32];
#pragma unroll
  for (int i = 0; i < 32; ++i) acc[i] = 0.f;

  const float* px = x + ((size_t)b * S + seg_start) * D + d0;

  float2 pfA[8], pfB[8];  // 2-group prefetch (compile-time indexed only)
  PF_GROUP(pfA, 0);
  PF_GROUP(pfB, 1);

  // ---- peeled j=0: groups 0..3 (first 15 frames have clamped tap windows) ----
#pragma unroll
  for (int f = 0; f < 8; ++f) FRAME_R(pfA[f], f, 0, f);
  PF_GROUP(pfA, 2);
#pragma unroll
  for (int f = 0; f < 8; ++f) FRAME_R(pfB[f], 8 + f, 0, ((8 + f) < 15 ? (8 + f) : 15));
  PF_GROUP(pfB, 3);
#pragma unroll
  for (int f = 0; f < 8; ++f) FRAME_R(pfA[f], 16 + f, 0, 15);
  FOLD(0, 0);
  PF_GROUP(pfA, 4);
#pragma unroll
  for (int f = 0; f < 8; ++f) FRAME_R(pfB[f], 24 + f, 0, 15);
  FOLD(8, 1);
  PF_GROUP(pfB, 5);

  // ---- rolled main: j=1..3, groups 4j..4j+3 (frames 32j..32j+31) ----
  for (int j = 1; j <= 3; ++j) {
    // i=0: consume pfA = group 4j; fold chunk 4j-2 (slots 16..23); pf 4j+2
#pragma unroll
    for (int f = 0; f < 8; ++f) FRAME_R(pfA[f], f, 0, 15);
    FOLD(16, 4 * j - 2);
    PF_GROUP(pfA, 4 * j + 2);
    // i=1: consume pfB = group 4j+1; fold chunk 4j-1 (slots 24..31); pf 4j+3
#pragma unroll
    for (int f = 0; f < 8; ++f) FRAME_R(pfB[f], 8 + f, 0, 15);
    FOLD(24, 4 * j - 1);
    PF_GROUP(pfB, 4 * j + 3);
    // i=2: consume pfA = group 4j+2; fold chunk 4j (slots 0..7); pf 4j+4
#pragma unroll
    for (int f = 0; f < 8; ++f) FRAME_R(pfA[f], 16 + f, 0, 15);
    FOLD(0, 4 * j);
    if (!tail || j < 3) PF_GROUP(pfA, 4 * j + 4);  // group 16 OOB only for tail
    // i=3: consume pfB = group 4j+3; fold chunk 4j+1 (slots 8..15); pf 4j+5
#pragma unroll
    for (int f = 0; f < 8; ++f) FRAME_R(pfB[f], 24 + f, 0, 15);
    FOLD(8, 4 * j + 1);
    if (!tail || j < 3) PF_GROUP(pfB, 4 * j + 5);  // group 17 OOB only for tail
  }

  // ---- epilogue: halo frames 128..142 (pfA=group 16, pfB=group 17),
  //      skipped for tail blocks (reference zero padding) ----
  if (!tail) {
#pragma unroll
    for (int t = 0; t < 8; ++t) FRAME_R(pfA[t], t, t + 1, 15);
  }
  FOLD(16, 14);
  if (!tail) {
#pragma unroll
    for (int t = 8; t < 15; ++t) FRAME_R(pfB[t - 8], t, t + 1, 15);
  }
  FOLD(24, 15);

  __syncthreads();

  // combine 4 wave-quarters + bias; one coalesced 512 B store per block
  if (tid < SEG) {
    const int c = tid >> 3, o = tid & 7;
    const float v =
        red[c][0][o] + red[c][1][o] + red[c][2][o] + red[c][3][o] + bias[0];
    out[(size_t)b * S + seg_start + tid] = v;
  }
}
}  // namespace

extern "C" void kernel_launch(void* const* d_in, const int* in_sizes, int n_in,
                              void* d_out, int out_size, void* d_ws, size_t ws_size,
                              hipStream_t stream) {
  const float* x = (const float*)d_in[0];
  const float* filt = (const float*)d_in[1];
  const float* bias = (const float*)d_in[2];
  float* out = (float*)d_out;

  hipLaunchKernelGGL(conv1d_kernel, dim3(NBLK), dim3(256), 0, stream,
                     x, filt, bias, out);
}

// Round 8
// 118.340 us; speedup vs baseline: 1.0162x; 1.0162x over previous
//
#include <hip/hip_runtime.h>

// conv1d: out[b,i] = sum_{k<16,d<512} x[b,i+k,d] * w[k,d] + bias, zero-pad at end.
// R7 = R5/R6 + amdgpu_waves_per_eu(4,4). R6 proved __launch_bounds__(256,4)
// does NOT stop the allocator targeting 8 waves/EU (VGPR=64, 86 MB spill).
// waves_per_eu(4,4) pins the occupancy target = register budget at 4 waves/EU
// (128 VGPR) -- free, since the 1024-block grid caps residency at 4 waves/SIMD.
// Structure unchanged: 128-output segment/block; lane owns 2 d's (float2);
// filter 32 VGPR; 32-slot compile-time acc ring; 2-group register prefetch
// (~1100 cy load->use); no hot-path branches/barriers; XCD-contiguous swizzle.

namespace {
constexpr int S = 4096;
constexpr int D = 512;
constexpr int K = 16;
constexpr int B = 32;
constexpr int SEG = 128;       // outputs per block
constexpr int NCH = SEG / 8;   // 16 chunks of 8 outputs
constexpr int SPR = S / SEG;   // 32 segments per row
constexpr int NBLK = B * SPR;  // 1024 blocks

// FMA one prefetched frame XV into ring slots ((FI - k) & 31); FI,KLO,KHI compile-time
#define FRAME_R(XV, FI, KLO, KHI)              \
  do {                                         \
    _Pragma("unroll")                          \
    for (int k = (KLO); k <= (KHI); ++k) {     \
      const int sl = ((FI) - k) & 31;          \
      acc[sl] = fmaf((XV).x, w[k].x, acc[sl]); \
      acc[sl] = fmaf((XV).y, w[k].y, acc[sl]); \
    }                                          \
  } while (0)

// issue 8 float2 loads of frame-group G into named prefetch regs DST[0..7]
#define PF_GROUP(DST, G)                                      \
  do {                                                        \
    const float* _pp = px + (size_t)(G) * (8 * D);            \
    _Pragma("unroll")                                         \
    for (int f = 0; f < 8; ++f)                               \
      DST[f] = *reinterpret_cast<const float2*>(_pp + f * D); \
  } while (0)

// fold 8 completed ring slots (SB..SB+7, SB compile-time) -> 64-lane sums;
// lane l<8 stores red[C][wv][perm(l)]  (validated in R4/R5/R6)
#define FOLD(SB, C)                                                           \
  do {                                                                        \
    float v[8];                                                               \
    _Pragma("unroll")                                                         \
    for (int i = 0; i < 8; ++i) {                                             \
      const int sl = ((SB) + i) & 31;                                         \
      v[i] = acc[sl];                                                         \
      acc[sl] = 0.f;                                                          \
    }                                                                         \
    const bool f0 = lane & 1, f1 = lane & 2, f2 = lane & 4;                   \
    _Pragma("unroll")                                                         \
    for (int j = 0; j < 4; ++j) {                                             \
      const float sv = f0 ? v[j] : v[j + 4];                                  \
      const float rv = __shfl_xor(sv, 1, 64);                                 \
      v[j] = (f0 ? v[j + 4] : v[j]) + rv;                                     \
    }                                                                         \
    _Pragma("unroll")                                                         \
    for (int j = 0; j < 2; ++j) {                                             \
      const float sv = f1 ? v[j] : v[j + 2];                                  \
      const float rv = __shfl_xor(sv, 2, 64);                                 \
      v[j] = (f1 ? v[j + 2] : v[j]) + rv;                                     \
    }                                                                         \
    {                                                                         \
      const float sv = f2 ? v[0] : v[1];                                      \
      const float rv = __shfl_xor(sv, 4, 64);                                 \
      float tt = (f2 ? v[1] : v[0]) + rv;                                     \
      tt += __shfl_xor(tt, 8, 64);                                            \
      tt += __shfl_xor(tt, 16, 64);                                           \
      tt += __shfl_xor(tt, 32, 64);                                           \
      if (lane < 8)                                                           \
        red[(C)][wv]                                                          \
           [4 * (lane & 1) + 2 * ((lane >> 1) & 1) + ((lane >> 2) & 1)] = tt; \
    }                                                                         \
  } while (0)

__global__ __launch_bounds__(256)
__attribute__((amdgpu_waves_per_eu(4, 4)))
void conv1d_kernel(const float* __restrict__ x,
                   const float* __restrict__ filt,
                   const float* __restrict__ bias,
                   float* __restrict__ out) {
  __shared__ float red[NCH][4][8];  // 2 KB
  const int tid = threadIdx.x;
  const int lane = tid & 63;
  const int wv = tid >> 6;
  const int d0 = wv * 128 + lane * 2;

  // XCD-contiguous swizzle (NBLK % 8 == 0)
  const int bid = blockIdx.x;
  const int lbid = (bid & 7) * (NBLK / 8) + (bid >> 3);
  const int b = lbid >> 5;        // / SPR
  const int seg = lbid & 31;
  const int seg_start = seg * SEG;
  const bool tail = (seg == SPR - 1);  // epilogue frames are zero padding

  float2 w[K];  // 32 VGPR
#pragma unroll
  for (int k = 0; k < K; ++k)
    w[k] = *reinterpret_cast<const float2*>(filt + k * D + d0);

  float acc[32];
#pragma unroll
  for (int i = 0; i < 32; ++i) acc[i] = 0.f;

  const float* px = x + ((size_t)b * S + seg_start) * D + d0;

  float2 pfA[8], pfB[8];  // 2-group prefetch (compile-time indexed only)
  PF_GROUP(pfA, 0);
  PF_GROUP(pfB, 1);

  // ---- peeled j=0: groups 0..3 (first 15 frames have clamped tap windows) ----
#pragma unroll
  for (int f = 0; f < 8; ++f) FRAME_R(pfA[f], f, 0, f);
  PF_GROUP(pfA, 2);
#pragma unroll
  for (int f = 0; f < 8; ++f) FRAME_R(pfB[f], 8 + f, 0, ((8 + f) < 15 ? (8 + f) : 15));
  PF_GROUP(pfB, 3);
#pragma unroll
  for (int f = 0; f < 8; ++f) FRAME_R(pfA[f], 16 + f, 0, 15);
  FOLD(0, 0);
  PF_GROUP(pfA, 4);
#pragma unroll
  for (int f = 0; f < 8; ++f) FRAME_R(pfB[f], 24 + f, 0, 15);
  FOLD(8, 1);
  PF_GROUP(pfB, 5);

  // ---- rolled main: j=1..3, groups 4j..4j+3 (frames 32j..32j+31) ----
  for (int j = 1; j <= 3; ++j) {
    // i=0: consume pfA = group 4j; fold chunk 4j-2 (slots 16..23); pf 4j+2
#pragma unroll
    for (int f = 0; f < 8; ++f) FRAME_R(pfA[f], f, 0, 15);
    FOLD(16, 4 * j - 2);
    PF_GROUP(pfA, 4 * j + 2);
    // i=1: consume pfB = group 4j+1; fold chunk 4j-1 (slots 24..31); pf 4j+3
#pragma unroll
    for (int f = 0; f < 8; ++f) FRAME_R(pfB[f], 8 + f, 0, 15);
    FOLD(24, 4 * j - 1);
    PF_GROUP(pfB, 4 * j + 3);
    // i=2: consume pfA = group 4j+2; fold chunk 4j (slots 0..7); pf 4j+4
#pragma unroll
    for (int f = 0; f < 8; ++f) FRAME_R(pfA[f], 16 + f, 0, 15);
    FOLD(0, 4 * j);
    if (!tail || j < 3) PF_GROUP(pfA, 4 * j + 4);  // group 16 OOB only for tail
    // i=3: consume pfB = group 4j+3; fold chunk 4j+1 (slots 8..15); pf 4j+5
#pragma unroll
    for (int f = 0; f < 8; ++f) FRAME_R(pfB[f], 24 + f, 0, 15);
    FOLD(8, 4 * j + 1);
    if (!tail || j < 3) PF_GROUP(pfB, 4 * j + 5);  // group 17 OOB only for tail
  }

  // ---- epilogue: halo frames 128..142 (pfA=group 16, pfB=group 17),
  //      skipped for tail blocks (reference zero padding) ----
  if (!tail) {
#pragma unroll
    for (int t = 0; t < 8; ++t) FRAME_R(pfA[t], t, t + 1, 15);
  }
  FOLD(16, 14);
  if (!tail) {
#pragma unroll
    for (int t = 8; t < 15; ++t) FRAME_R(pfB[t - 8], t, t + 1, 15);
  }
  FOLD(24, 15);

  __syncthreads();

  // combine 4 wave-quarters + bias; one coalesced 512 B store per block
  if (tid < SEG) {
    const int c = tid >> 3, o = tid & 7;
    const float v =
        red[c][0][o] + red[c][1][o] + red[c][2][o] + red[c][3][o] + bias[0];
    out[(size_t)b * S + seg_start + tid] = v;
  }
}
}  // namespace

extern "C" void kernel_launch(void* const* d_in, const int* in_sizes, int n_in,
                              void* d_out, int out_size, void* d_ws, size_t ws_size,
                              hipStream_t stream) {
  const float* x = (const float*)d_in[0];
  const float* filt = (const float*)d_in[1];
  const float* bias = (const float*)d_in[2];
  float* out = (float*)d_out;

  hipLaunchKernelGGL(conv1d_kernel, dim3(NBLK), dim3(256), 0, stream,
                     x, filt, bias, out);
}

// Round 9
// 87.819 us; speedup vs baseline: 1.3694x; 1.3475x over previous
//
#include <hip/hip_runtime.h>

// conv1d: out[b,i] = sum_{k<16,d<512} x[b,i+k,d] * w[k,d] + bias, zero-pad at end.
// R8: fit the 64-VGPR attractor instead of fighting the allocator (R5-R7 all
// spilled at VGPR=64 with ~115-reg demand). 512-thr block = 8 waves =
// {tap-half h} x {d-quarter q}; lane owns 2 d's. Per wave: w[8] float2 = 16
// VGPR, acc ring 16 (window 8 taps + 7 = 15), prefetch 2 x 4-frame x float2
// = 16. Demand ~56 -> zero spill AND 8 waves/SIMD (100% occupancy, 2x the
// latency hiding of any prior round). Branch-free compile-time ring; wave-
// uniform tail guards at group granularity; validated FOLD butterfly in-place.
// Wave h reads frames phi+8h; the 8-frame-lagged re-read of the other half
// hits L2 (HBM traffic stays ~300 MB).

namespace {
constexpr int S = 4096;
constexpr int D = 512;
constexpr int B = 32;
constexpr int SEG = 128;        // outputs per block
constexpr int SPR = S / SEG;    // 32 segments per row
constexpr int NBLK = B * SPR;   // 1024 blocks

// FMA one prefetched frame XV (float2) into ring slots ((PHI16 - k) & 15);
// PHI16 = phi mod 16, KLO/KHI compile-time after unrolling.
#define FRAME(XV, PHI16, KLO, KHI)             \
  do {                                         \
    _Pragma("unroll")                          \
    for (int k = (KLO); k <= (KHI); ++k) {     \
      const int sl = ((PHI16) - k) & 15;       \
      acc[sl] = fmaf((XV).x, w[k].x, acc[sl]); \
      acc[sl] = fmaf((XV).y, w[k].y, acc[sl]); \
    }                                          \
  } while (0)

// consume a full-tap 4-frame group G from BUF (guarded for tail blocks)
#define CONSUME_FULL(BUF, G, PHI0)           \
  do {                                       \
    if ((G) < glim) {                        \
      FRAME(BUF[0], (PHI0) + 0, 0, 7);       \
      FRAME(BUF[1], (PHI0) + 1, 0, 7);       \
      FRAME(BUF[2], (PHI0) + 2, 0, 7);       \
      FRAME(BUF[3], (PHI0) + 3, 0, 7);       \
    }                                        \
  } while (0)

// prefetch 4 frames of group G into DST (guarded); pointer advances always
#define PF(DST, G)                                              \
  do {                                                          \
    if ((G) < glim) {                                           \
      _Pragma("unroll")                                         \
      for (int t = 0; t < 4; ++t)                               \
        DST[t] = *reinterpret_cast<const float2*>(pfp + t * D); \
    }                                                           \
    pfp += 4 * D;                                               \
  } while (0)

// fold ring slots SB..SB+7 (outputs 8C..8C+7) in-place across 64 lanes;
// dataflow identical to the R4-R7-validated FOLD, minus the v[] copies.
#define FOLD(SB, C)                                                           \
  do {                                                                        \
    const bool f0 = lane & 1, f1 = lane & 2, f2 = lane & 4;                   \
    _Pragma("unroll")                                                         \
    for (int j = 0; j < 4; ++j) {                                             \
      const float sv = f0 ? acc[(SB) + j] : acc[(SB) + j + 4];                \
      const float rv = __shfl_xor(sv, 1, 64);                                 \
      acc[(SB) + j] = (f0 ? acc[(SB) + j + 4] : acc[(SB) + j]) + rv;          \
    }                                                                         \
    _Pragma("unroll")                                                         \
    for (int j = 0; j < 2; ++j) {                                             \
      const float sv = f1 ? acc[(SB) + j] : acc[(SB) + j + 2];                \
      const float rv = __shfl_xor(sv, 2, 64);                                 \
      acc[(SB) + j] = (f1 ? acc[(SB) + j + 2] : acc[(SB) + j]) + rv;          \
    }                                                                         \
    {                                                                         \
      const float sv = f2 ? acc[(SB)] : acc[(SB) + 1];                        \
      const float rv = __shfl_xor(sv, 4, 64);                                 \
      float tt = (f2 ? acc[(SB) + 1] : acc[(SB)]) + rv;                       \
      tt += __shfl_xor(tt, 8, 64);                                            \
      tt += __shfl_xor(tt, 16, 64);                                           \
      tt += __shfl_xor(tt, 32, 64);                                           \
      if (lane < 8)                                                           \
        red[(C)][wv]                                                          \
           [4 * (lane & 1) + 2 * ((lane >> 1) & 1) + ((lane >> 2) & 1)] = tt; \
    }                                                                         \
    _Pragma("unroll")                                                         \
    for (int i = 0; i < 8; ++i) acc[(SB) + i] = 0.f;                          \
  } while (0)

__global__ __launch_bounds__(512)
void conv1d_kernel(const float* __restrict__ x,
                   const float* __restrict__ filt,
                   const float* __restrict__ bias,
                   float* __restrict__ out) {
  __shared__ float red[16][8][8];  // 4 KB: [chunk][wave][output-in-chunk]
  const int tid = threadIdx.x;
  const int lane = tid & 63;
  const int wv = tid >> 6;   // 0..7
  const int h = wv >> 2;     // tap half: taps 8h..8h+7
  const int q = wv & 3;      // d quarter
  const int d0 = q * 128 + lane * 2;

  // XCD-contiguous swizzle (NBLK % 8 == 0)
  const int bid = blockIdx.x;
  const int lbid = (bid & 7) * (NBLK / 8) + (bid >> 3);
  const int b = lbid >> 5;   // / SPR
  const int seg = lbid & 31;
  const int seg_start = seg * SEG;
  // wave's group g valid iff frames 4g+8h .. < 128 stay in-row for tail seg
  const bool tail = (seg == SPR - 1);
  const int glim = tail ? (32 - 2 * h) : 34;  // groups < glim are valid

  // filter: this wave's 8 taps, lane's 2 d's = 16 VGPR
  float2 w[8];
#pragma unroll
  for (int k = 0; k < 8; ++k)
    w[k] = *reinterpret_cast<const float2*>(filt + (8 * h + k) * D + d0);

  float acc[16];
#pragma unroll
  for (int i = 0; i < 16; ++i) acc[i] = 0.f;

  // frame phi of this wave lives at pfp0 + phi*D (f = phi + 8h)
  const float* pfp = x + ((size_t)b * S + seg_start + 8 * h) * D + d0;

  float2 pfA[4], pfB[4];  // 2 x 4-frame prefetch (compile-time indexed)
  PF(pfA, 0);
  PF(pfB, 1);

  // ---- prologue: groups 0..7 (phi 0..31); clamped taps for phi < 7 ----
  if (0 < glim) {
    FRAME(pfA[0], 0, 0, 0); FRAME(pfA[1], 1, 0, 1);
    FRAME(pfA[2], 2, 0, 2); FRAME(pfA[3], 3, 0, 3);
  }
  PF(pfA, 2);
  if (1 < glim) {
    FRAME(pfB[0], 4, 0, 4); FRAME(pfB[1], 5, 0, 5);
    FRAME(pfB[2], 6, 0, 6); FRAME(pfB[3], 7, 0, 7);
  }
  PF(pfB, 3);
  CONSUME_FULL(pfA, 2, 8);
  PF(pfA, 4);
  CONSUME_FULL(pfB, 3, 12);
  FOLD(0, 0);
  PF(pfB, 5);
  CONSUME_FULL(pfA, 4, 0);
  PF(pfA, 6);
  CONSUME_FULL(pfB, 5, 4);
  FOLD(8, 1);
  PF(pfB, 7);
  CONSUME_FULL(pfA, 6, 8);
  PF(pfA, 8);
  CONSUME_FULL(pfB, 7, 12);
  FOLD(0, 2);
  PF(pfB, 9);

  // ---- main: JJ = 2..7, groups 4JJ..4JJ+3 (16 frames/iter = ring period) ----
  for (int JJ = 2; JJ <= 7; ++JJ) {
    const int g0 = 4 * JJ;
    CONSUME_FULL(pfA, g0, 0);
    PF(pfA, g0 + 2);
    CONSUME_FULL(pfB, g0 + 1, 4);
    FOLD(8, 2 * JJ - 1);
    PF(pfB, g0 + 3);
    CONSUME_FULL(pfA, g0 + 2, 8);
    PF(pfA, g0 + 4);
    CONSUME_FULL(pfB, g0 + 3, 12);
    FOLD(0, 2 * JJ);
    PF(pfB, g0 + 5);
  }

  // ---- epilogue: groups 32,33 (phi 128..134, klo = phi-127) ----
  if (32 < glim) {
    FRAME(pfA[0], 0, 1, 7); FRAME(pfA[1], 1, 2, 7);
    FRAME(pfA[2], 2, 3, 7); FRAME(pfA[3], 3, 4, 7);
  }
  if (33 < glim) {
    FRAME(pfB[0], 4, 5, 7); FRAME(pfB[1], 5, 6, 7);
    FRAME(pfB[2], 6, 7, 7);
  }
  FOLD(8, 15);

  __syncthreads();

  // combine the 8 wave-partials per output + bias; coalesced 512 B store
  if (tid < SEG) {
    const int c = tid >> 3, o = tid & 7;
    float v = bias[0];
#pragma unroll
    for (int wvi = 0; wvi < 8; ++wvi) v += red[c][wvi][o];
    out[(size_t)b * S + seg_start + tid] = v;
  }
}
}  // namespace

extern "C" void kernel_launch(void* const* d_in, const int* in_sizes, int n_in,
                              void* d_out, int out_size, void* d_ws, size_t ws_size,
                              hipStream_t stream) {
  const float* x = (const float*)d_in[0];
  const float* filt = (const float*)d_in[1];
  const float* bias = (const float*)d_in[2];
  float* out = (float*)d_out;

  hipLaunchKernelGGL(conv1d_kernel, dim3(NBLK), dim3(512), 0, stream,
                     x, filt, bias, out);
}

// Round 10
// 75.830 us; speedup vs baseline: 1.5859x; 1.1581x over previous
//
#include <hip/hip_runtime.h>

// conv1d: out[b,i] = sum_{k<16,d<512} x[b,i+k,d] * w[k,d] + bias, zero-pad at end.
// R9 = R8 + 3-deep prefetch rotation (the single change). R8's main loop
// consumed pfA only ~1 consume after its PF (~150-300 cy cover vs ~900 cy HBM
// latency). R9 keeps PF exactly 3 groups ahead (cover ~2 consumes+fold
// ~450-700 cy, 12 loads in flight/wave). Register budget stays on the 64-VGPR
// attractor: w[8]x2=16 + acc[16]=16 + pf 3x4x2=24 + addr ~ 60.
// All else identical to the passing R8: 512-thr block = {tap-half h} x
// {d-quarter q}; compile-time 16-slot ring; glim tail guards; XCD swizzle.

namespace {
constexpr int S = 4096;
constexpr int D = 512;
constexpr int B = 32;
constexpr int SEG = 128;        // outputs per block
constexpr int SPR = S / SEG;    // 32 segments per row
constexpr int NBLK = B * SPR;   // 1024 blocks

// FMA one prefetched frame XV (float2) into ring slots ((PHI16 - k) & 15)
#define FRAME(XV, PHI16, KLO, KHI)             \
  do {                                         \
    _Pragma("unroll")                          \
    for (int k = (KLO); k <= (KHI); ++k) {     \
      const int sl = ((PHI16) - k) & 15;       \
      acc[sl] = fmaf((XV).x, w[k].x, acc[sl]); \
      acc[sl] = fmaf((XV).y, w[k].y, acc[sl]); \
    }                                          \
  } while (0)

// consume a full-tap 4-frame group G from BUF (guarded for tail blocks)
#define CONSUME(BUF, G, PHI0)          \
  do {                                 \
    if ((G) < glim) {                  \
      FRAME(BUF[0], (PHI0) + 0, 0, 7); \
      FRAME(BUF[1], (PHI0) + 1, 0, 7); \
      FRAME(BUF[2], (PHI0) + 2, 0, 7); \
      FRAME(BUF[3], (PHI0) + 3, 0, 7); \
    }                                  \
  } while (0)

// prefetch 4 frames of group G into DST (guarded); pointer advances always
#define PF(DST, G)                                              \
  do {                                                          \
    if ((G) < glim) {                                           \
      _Pragma("unroll")                                         \
      for (int t = 0; t < 4; ++t)                               \
        DST[t] = *reinterpret_cast<const float2*>(pfp + t * D); \
    }                                                           \
    pfp += 4 * D;                                               \
  } while (0)

// fold ring slots SB..SB+7 (outputs 8C..8C+7) in-place across 64 lanes
#define FOLD(SB, C)                                                           \
  do {                                                                        \
    const bool f0 = lane & 1, f1 = lane & 2, f2 = lane & 4;                   \
    _Pragma("unroll")                                                         \
    for (int j = 0; j < 4; ++j) {                                             \
      const float sv = f0 ? acc[(SB) + j] : acc[(SB) + j + 4];                \
      const float rv = __shfl_xor(sv, 1, 64);                                 \
      acc[(SB) + j] = (f0 ? acc[(SB) + j + 4] : acc[(SB) + j]) + rv;          \
    }                                                                         \
    _Pragma("unroll")                                                         \
    for (int j = 0; j < 2; ++j) {                                             \
      const float sv = f1 ? acc[(SB) + j] : acc[(SB) + j + 2];                \
      const float rv = __shfl_xor(sv, 2, 64);                                 \
      acc[(SB) + j] = (f1 ? acc[(SB) + j + 2] : acc[(SB) + j]) + rv;          \
    }                                                                         \
    {                                                                         \
      const float sv = f2 ? acc[(SB)] : acc[(SB) + 1];                        \
      const float rv = __shfl_xor(sv, 4, 64);                                 \
      float tt = (f2 ? acc[(SB) + 1] : acc[(SB)]) + rv;                       \
      tt += __shfl_xor(tt, 8, 64);                                            \
      tt += __shfl_xor(tt, 16, 64);                                           \
      tt += __shfl_xor(tt, 32, 64);                                           \
      if (lane < 8)                                                           \
        red[(C)][wv]                                                          \
           [4 * (lane & 1) + 2 * ((lane >> 1) & 1) + ((lane >> 2) & 1)] = tt; \
    }                                                                         \
    _Pragma("unroll")                                                         \
    for (int i = 0; i < 8; ++i) acc[(SB) + i] = 0.f;                          \
  } while (0)

__global__ __launch_bounds__(512)
void conv1d_kernel(const float* __restrict__ x,
                   const float* __restrict__ filt,
                   const float* __restrict__ bias,
                   float* __restrict__ out) {
  __shared__ float red[16][8][8];  // 4 KB: [chunk][wave][output-in-chunk]
  const int tid = threadIdx.x;
  const int lane = tid & 63;
  const int wv = tid >> 6;   // 0..7
  const int h = wv >> 2;     // tap half: taps 8h..8h+7
  const int q = wv & 3;      // d quarter
  const int d0 = q * 128 + lane * 2;

  // XCD-contiguous swizzle (NBLK % 8 == 0)
  const int bid = blockIdx.x;
  const int lbid = (bid & 7) * (NBLK / 8) + (bid >> 3);
  const int b = lbid >> 5;   // / SPR
  const int seg = lbid & 31;
  const int seg_start = seg * SEG;
  const bool tail = (seg == SPR - 1);
  const int glim = tail ? (32 - 2 * h) : 34;  // groups < glim are valid

  // filter: this wave's 8 taps, lane's 2 d's = 16 VGPR
  float2 w[8];
#pragma unroll
  for (int k = 0; k < 8; ++k)
    w[k] = *reinterpret_cast<const float2*>(filt + (8 * h + k) * D + d0);

  float acc[16];
#pragma unroll
  for (int i = 0; i < 16; ++i) acc[i] = 0.f;

  // wave's frame phi lives at pfp0 + phi*D (global frame f = phi + 8h)
  const float* pfp = x + ((size_t)b * S + seg_start + 8 * h) * D + d0;

  float2 pfA[4], pfB[4], pfC[4];  // 3-deep prefetch (compile-time indexed)
  PF(pfA, 0);
  PF(pfB, 1);
  PF(pfC, 2);

  // ---- prologue: groups 0..7; clamped taps for phi < 7 ----
  if (0 < glim) {
    FRAME(pfA[0], 0, 0, 0); FRAME(pfA[1], 1, 0, 1);
    FRAME(pfA[2], 2, 0, 2); FRAME(pfA[3], 3, 0, 3);
  }
  PF(pfA, 3);
  if (1 < glim) {
    FRAME(pfB[0], 4, 0, 4); FRAME(pfB[1], 5, 0, 5);
    FRAME(pfB[2], 6, 0, 6); FRAME(pfB[3], 7, 0, 7);
  }
  PF(pfB, 4);
  CONSUME(pfC, 2, 8);
  PF(pfC, 5);
  CONSUME(pfA, 3, 12);
  FOLD(0, 0);
  PF(pfA, 6);
  CONSUME(pfB, 4, 0);
  PF(pfB, 7);
  CONSUME(pfC, 5, 4);
  FOLD(8, 1);
  PF(pfC, 8);
  CONSUME(pfA, 6, 8);
  PF(pfA, 9);
  CONSUME(pfB, 7, 12);
  FOLD(0, 2);
  PF(pfB, 10);

  // ---- main: II = 0..1, 12 groups each (buffer = G%3, phi0 = 4G mod 16) ----
  for (int II = 0; II <= 1; ++II) {
    const int G0 = 8 + 12 * II;
    const int c0 = 3 + 6 * II;
    CONSUME(pfC, G0 + 0, 0);
    PF(pfC, G0 + 3);
    CONSUME(pfA, G0 + 1, 4);
    FOLD(8, c0 + 0);
    PF(pfA, G0 + 4);
    CONSUME(pfB, G0 + 2, 8);
    PF(pfB, G0 + 5);
    CONSUME(pfC, G0 + 3, 12);
    FOLD(0, c0 + 1);
    PF(pfC, G0 + 6);
    CONSUME(pfA, G0 + 4, 0);
    PF(pfA, G0 + 7);
    CONSUME(pfB, G0 + 5, 4);
    FOLD(8, c0 + 2);
    PF(pfB, G0 + 8);
    CONSUME(pfC, G0 + 6, 8);
    PF(pfC, G0 + 9);
    CONSUME(pfA, G0 + 7, 12);
    FOLD(0, c0 + 3);
    PF(pfA, G0 + 10);
    CONSUME(pfB, G0 + 8, 0);
    PF(pfB, G0 + 11);
    CONSUME(pfC, G0 + 9, 4);
    FOLD(8, c0 + 4);
    PF(pfC, G0 + 12);
    CONSUME(pfA, G0 + 10, 8);
    PF(pfA, G0 + 13);
    CONSUME(pfB, G0 + 11, 12);
    FOLD(0, c0 + 5);
    PF(pfB, G0 + 14);  // II=1: G=34, guarded off (glim<=34 always)
  }

  // ---- epilogue: groups 32 (pfC) and 33 (pfA), phi 128..134, klo = phi-127 ----
  if (32 < glim) {
    FRAME(pfC[0], 0, 1, 7); FRAME(pfC[1], 1, 2, 7);
    FRAME(pfC[2], 2, 3, 7); FRAME(pfC[3], 3, 4, 7);
  }
  if (33 < glim) {
    FRAME(pfA[0], 4, 5, 7); FRAME(pfA[1], 5, 6, 7);
    FRAME(pfA[2], 6, 7, 7);
  }
  FOLD(8, 15);

  __syncthreads();

  // combine the 8 wave-partials per output + bias; coalesced 512 B store
  if (tid < SEG) {
    const int c = tid >> 3, o = tid & 7;
    float v = bias[0];
#pragma unroll
    for (int wvi = 0; wvi < 8; ++wvi) v += red[c][wvi][o];
    out[(size_t)b * S + seg_start + tid] = v;
  }
}
}  // namespace

extern "C" void kernel_launch(void* const* d_in, const int* in_sizes, int n_in,
                              void* d_out, int out_size, void* d_ws, size_t ws_size,
                              hipStream_t stream) {
  const float* x = (const float*)d_in[0];
  const float* filt = (const float*)d_in[1];
  const float* bias = (const float*)d_in[2];
  float* out = (float*)d_out;

  hipLaunchKernelGGL(conv1d_kernel, dim3(NBLK), dim3(512), 0, stream,
                     x, filt, bias, out);
}

// Round 11
// 52.954 us; speedup vs baseline: 2.2710x; 1.4320x over previous
//
#include <hip/hip_runtime.h>

// conv1d: out[b,i] = sum_{k<16,d<512} x[b,i+k,d] * w[k,d] + bias, zero-pad at end.
// R10: 1 d per lane (d = tid), FULL 16 taps per wave -> each frame issued to
// the memory system exactly ONCE (R9's tap-split issued 2x, 256 MB of L2
// re-reads). Regs: w[16]=16 + acc ring 24 (16-tap window needs 23 live) +
// 4-deep x 4-frame x dword prefetch = 16 -> ~62, on the 64-VGPR attractor
// with a 3-consume-gap prefetch distance (1.5x R9). 12-group rolled main
// body (period lcm(4 bufs, ring 24/4) = 12); peeled prologue/epilogue carry
// all tap clamps; wave-uniform G<glim guards (R8/R9-proven); XCD swizzle.

namespace {
constexpr int S = 4096;
constexpr int D = 512;
constexpr int B = 32;
constexpr int SEG = 128;        // outputs per block
constexpr int SPR = S / SEG;    // 32 segments per row
constexpr int NBLK = B * SPR;   // 1024 blocks

// FMA one prefetched frame XV (scalar) into ring slots ((PHI24 - k) mod 24)
#define FRAME(XV, PHI24, KLO, KHI)               \
  do {                                           \
    _Pragma("unroll")                            \
    for (int k = (KLO); k <= (KHI); ++k) {       \
      const int sl = ((PHI24) - k + 24) % 24;    \
      acc[sl] = fmaf((XV), w[k], acc[sl]);       \
    }                                            \
  } while (0)

// consume full-tap 4-frame group G from BUF (guarded for tail blocks)
#define CONSUME(BUF, G, PHI0)           \
  do {                                  \
    if ((G) < glim) {                   \
      FRAME(BUF[0], (PHI0) + 0, 0, 15); \
      FRAME(BUF[1], (PHI0) + 1, 0, 15); \
      FRAME(BUF[2], (PHI0) + 2, 0, 15); \
      FRAME(BUF[3], (PHI0) + 3, 0, 15); \
    }                                   \
  } while (0)

// prefetch 4 frames of group G into DST (guarded); pointer advances always
#define PF(DST, G)                   \
  do {                               \
    if ((G) < glim) {                \
      _Pragma("unroll")              \
      for (int t = 0; t < 4; ++t)    \
        DST[t] = pfp[(size_t)t * D]; \
    }                                \
    pfp += (size_t)4 * D;            \
  } while (0)

// fold ring slots SB..SB+7 (outputs 8C..8C+7) in-place across 64 lanes;
// dataflow validated in R4-R9 (passed absmax every round)
#define FOLD(SB, C)                                                           \
  do {                                                                        \
    const bool f0 = lane & 1, f1 = lane & 2, f2 = lane & 4;                   \
    _Pragma("unroll")                                                         \
    for (int j = 0; j < 4; ++j) {                                             \
      const float sv = f0 ? acc[(SB) + j] : acc[(SB) + j + 4];                \
      const float rv = __shfl_xor(sv, 1, 64);                                 \
      acc[(SB) + j] = (f0 ? acc[(SB) + j + 4] : acc[(SB) + j]) + rv;          \
    }                                                                         \
    _Pragma("unroll")                                                         \
    for (int j = 0; j < 2; ++j) {                                             \
      const float sv = f1 ? acc[(SB) + j] : acc[(SB) + j + 2];                \
      const float rv = __shfl_xor(sv, 2, 64);                                 \
      acc[(SB) + j] = (f1 ? acc[(SB) + j + 2] : acc[(SB) + j]) + rv;          \
    }                                                                         \
    {                                                                         \
      const float sv = f2 ? acc[(SB)] : acc[(SB) + 1];                        \
      const float rv = __shfl_xor(sv, 4, 64);                                 \
      float tt = (f2 ? acc[(SB) + 1] : acc[(SB)]) + rv;                       \
      tt += __shfl_xor(tt, 8, 64);                                            \
      tt += __shfl_xor(tt, 16, 64);                                           \
      tt += __shfl_xor(tt, 32, 64);                                           \
      if (lane < 8)                                                           \
        red[(C)][wv]                                                          \
           [4 * (lane & 1) + 2 * ((lane >> 1) & 1) + ((lane >> 2) & 1)] = tt; \
    }                                                                         \
    _Pragma("unroll")                                                         \
    for (int i = 0; i < 8; ++i) acc[(SB) + i] = 0.f;                          \
  } while (0)

__global__ __launch_bounds__(512)
void conv1d_kernel(const float* __restrict__ x,
                   const float* __restrict__ filt,
                   const float* __restrict__ bias,
                   float* __restrict__ out) {
  __shared__ float red[16][8][8];  // 4 KB: [chunk][wave][output-in-chunk]
  const int tid = threadIdx.x;
  const int lane = tid & 63;
  const int wv = tid >> 6;   // 0..7

  // XCD-contiguous swizzle (NBLK % 8 == 0)
  const int bid = blockIdx.x;
  const int lbid = (bid & 7) * (NBLK / 8) + (bid >> 3);
  const int b = lbid >> 5;   // / SPR
  const int seg = lbid & 31;
  const int seg_start = seg * SEG;
  const bool tail = (seg == SPR - 1);
  // frames phi 0..142 (groups 0..35) for interior; tail: phi < 128 (gr < 32),
  // the rest is the reference's zero padding (skipped = adds zero)
  const int glim = tail ? 32 : 36;

  // filter column d = tid for all 16 taps: 16 VGPR
  float w[16];
#pragma unroll
  for (int k = 0; k < 16; ++k) w[k] = filt[k * D + tid];

  float acc[24];
#pragma unroll
  for (int i = 0; i < 24; ++i) acc[i] = 0.f;

  // lane's element of frame phi lives at pfp0 + phi*D
  const float* pfp = x + ((size_t)b * S + seg_start) * D + tid;

  float pfA[4], pfB[4], pfC[4], pfD[4];  // 4-deep prefetch, 16 VGPR total
  PF(pfA, 0);
  PF(pfB, 1);
  PF(pfC, 2);
  PF(pfD, 3);

  // ---- prologue: groups 0..5 (phi 0..23); khi clamped to phi for phi<15 ----
  FRAME(pfA[0], 0, 0, 0); FRAME(pfA[1], 1, 0, 1);
  FRAME(pfA[2], 2, 0, 2); FRAME(pfA[3], 3, 0, 3);
  PF(pfA, 4);
  FRAME(pfB[0], 4, 0, 4); FRAME(pfB[1], 5, 0, 5);
  FRAME(pfB[2], 6, 0, 6); FRAME(pfB[3], 7, 0, 7);
  PF(pfB, 5);
  FRAME(pfC[0], 8, 0, 8); FRAME(pfC[1], 9, 0, 9);
  FRAME(pfC[2], 10, 0, 10); FRAME(pfC[3], 11, 0, 11);
  PF(pfC, 6);
  FRAME(pfD[0], 12, 0, 12); FRAME(pfD[1], 13, 0, 13);
  FRAME(pfD[2], 14, 0, 14); FRAME(pfD[3], 15, 0, 15);
  PF(pfD, 7);
  CONSUME(pfA, 4, 16);
  PF(pfA, 8);
  CONSUME(pfB, 5, 20);
  FOLD(0, 0);
  PF(pfB, 9);

  // ---- rolled main: two 12-group bodies, groups 6..17 and 18..29 ----
  for (int g0 = 6; g0 <= 18; g0 += 12) {
    const int cb = (g0 - 4) / 2;  // fold chunk base: 1 or 7
    CONSUME(pfC, g0 + 0, 0);
    PF(pfC, g0 + 4);
    CONSUME(pfD, g0 + 1, 4);
    FOLD(8, cb);
    PF(pfD, g0 + 5);
    CONSUME(pfA, g0 + 2, 8);
    PF(pfA, g0 + 6);
    CONSUME(pfB, g0 + 3, 12);
    FOLD(16, cb + 1);
    PF(pfB, g0 + 7);
    CONSUME(pfC, g0 + 4, 16);
    PF(pfC, g0 + 8);
    CONSUME(pfD, g0 + 5, 20);
    FOLD(0, cb + 2);
    PF(pfD, g0 + 9);
    CONSUME(pfA, g0 + 6, 0);
    PF(pfA, g0 + 10);
    CONSUME(pfB, g0 + 7, 4);
    FOLD(8, cb + 3);
    PF(pfB, g0 + 11);
    CONSUME(pfC, g0 + 8, 8);
    PF(pfC, g0 + 12);
    CONSUME(pfD, g0 + 9, 12);
    FOLD(16, cb + 4);
    PF(pfD, g0 + 13);
    CONSUME(pfA, g0 + 10, 16);
    PF(pfA, g0 + 14);
    CONSUME(pfB, g0 + 11, 20);
    FOLD(0, cb + 5);
    PF(pfB, g0 + 15);
  }

  // ---- epilogue: groups 30..35 (phi 120..142); klo = phi-127 for phi>127 ----
  CONSUME(pfC, 30, 0);
  PF(pfC, 34);
  CONSUME(pfD, 31, 4);
  FOLD(8, 13);
  PF(pfD, 35);
  if (32 < glim) {
    FRAME(pfA[0], 8, 1, 15); FRAME(pfA[1], 9, 2, 15);
    FRAME(pfA[2], 10, 3, 15); FRAME(pfA[3], 11, 4, 15);
  }
  if (33 < glim) {
    FRAME(pfB[0], 12, 5, 15); FRAME(pfB[1], 13, 6, 15);
    FRAME(pfB[2], 14, 7, 15); FRAME(pfB[3], 15, 8, 15);
  }
  FOLD(16, 14);
  if (34 < glim) {
    FRAME(pfC[0], 16, 9, 15); FRAME(pfC[1], 17, 10, 15);
    FRAME(pfC[2], 18, 11, 15); FRAME(pfC[3], 19, 12, 15);
  }
  if (35 < glim) {
    FRAME(pfD[0], 20, 13, 15); FRAME(pfD[1], 21, 14, 15);
    FRAME(pfD[2], 22, 15, 15);  // phi 143 has no valid taps
  }
  FOLD(0, 15);

  __syncthreads();

  // combine the 8 wave-partials per output + bias; coalesced 512 B store
  if (tid < SEG) {
    const int c = tid >> 3, o = tid & 7;
    float v = bias[0];
#pragma unroll
    for (int wvi = 0; wvi < 8; ++wvi) v += red[c][wvi][o];
    out[(size_t)b * S + seg_start + tid] = v;
  }
}
}  // namespace

extern "C" void kernel_launch(void* const* d_in, const int* in_sizes, int n_in,
                              void* d_out, int out_size, void* d_ws, size_t ws_size,
                              hipStream_t stream) {
  const float* x = (const float*)d_in[0];
  const float* filt = (const float*)d_in[1];
  const float* bias = (const float*)d_in[2];
  float* out = (float*)d_out;

  hipLaunchKernelGGL(conv1d_kernel, dim3(NBLK), dim3(512), 0, stream,
                     x, filt, bias, out);
}

// Round 12
// 52.121 us; speedup vs baseline: 2.3073x; 1.0160x over previous
//
#include <hip/hip_runtime.h>

// conv1d: out[b,i] = sum_{k<16,d<512} x[b,i+k,d] * w[k,d] + bias, zero-pad at end.
// R11 = R10 with SEG 128 -> 256: halo HBM over-fetch drops 11.7% -> 5.9%
// (R5 counters proved halo is NOT L2-absorbed across blocks). Occupancy
// halves (2 blocks/CU, 4 waves/SIMD) but the kernel is HBM-BW-bound:
// in-flight bytes ~64 KB/CU >> 9 KB Little's-law minimum. All R10-proven
// machinery unchanged: 1 d/lane (d=tid), full 16 taps/wave (one read per
// frame), ring-24 acc with fold-after-group-2c+5 cadence, 4-deep 4-frame
// prefetch (buffer = G mod 4), wave-uniform G<glim tail guards, XCD swizzle.

namespace {
constexpr int S = 4096;
constexpr int D = 512;
constexpr int B = 32;
constexpr int SEG = 256;        // outputs per block
constexpr int SPR = S / SEG;    // 16 segments per row
constexpr int NBLK = B * SPR;   // 512 blocks

// FMA one prefetched frame XV (scalar) into ring slots ((PHI24 - k) mod 24)
#define FRAME(XV, PHI24, KLO, KHI)               \
  do {                                           \
    _Pragma("unroll")                            \
    for (int k = (KLO); k <= (KHI); ++k) {       \
      const int sl = ((PHI24) - k + 24) % 24;    \
      acc[sl] = fmaf((XV), w[k], acc[sl]);       \
    }                                            \
  } while (0)

// consume full-tap 4-frame group G from BUF (guarded for tail blocks)
#define CONSUME(BUF, G, PHI0)           \
  do {                                  \
    if ((G) < glim) {                   \
      FRAME(BUF[0], (PHI0) + 0, 0, 15); \
      FRAME(BUF[1], (PHI0) + 1, 0, 15); \
      FRAME(BUF[2], (PHI0) + 2, 0, 15); \
      FRAME(BUF[3], (PHI0) + 3, 0, 15); \
    }                                   \
  } while (0)

// prefetch 4 frames of group G into DST (guarded); pointer advances always
#define PF(DST, G)                   \
  do {                               \
    if ((G) < glim) {                \
      _Pragma("unroll")              \
      for (int t = 0; t < 4; ++t)    \
        DST[t] = pfp[(size_t)t * D]; \
    }                                \
    pfp += (size_t)4 * D;            \
  } while (0)

// fold ring slots SB..SB+7 (outputs 8C..8C+7) in-place across 64 lanes;
// dataflow validated R4-R10
#define FOLD(SB, C)                                                           \
  do {                                                                        \
    const bool f0 = lane & 1, f1 = lane & 2, f2 = lane & 4;                   \
    _Pragma("unroll")                                                         \
    for (int j = 0; j < 4; ++j) {                                             \
      const float sv = f0 ? acc[(SB) + j] : acc[(SB) + j + 4];                \
      const float rv = __shfl_xor(sv, 1, 64);                                 \
      acc[(SB) + j] = (f0 ? acc[(SB) + j + 4] : acc[(SB) + j]) + rv;          \
    }                                                                         \
    _Pragma("unroll")                                                         \
    for (int j = 0; j < 2; ++j) {                                             \
      const float sv = f1 ? acc[(SB) + j] : acc[(SB) + j + 2];                \
      const float rv = __shfl_xor(sv, 2, 64);                                 \
      acc[(SB) + j] = (f1 ? acc[(SB) + j + 2] : acc[(SB) + j]) + rv;          \
    }                                                                         \
    {                                                                         \
      const float sv = f2 ? acc[(SB)] : acc[(SB) + 1];                        \
      const float rv = __shfl_xor(sv, 4, 64);                                 \
      float tt = (f2 ? acc[(SB) + 1] : acc[(SB)]) + rv;                       \
      tt += __shfl_xor(tt, 8, 64);                                            \
      tt += __shfl_xor(tt, 16, 64);                                           \
      tt += __shfl_xor(tt, 32, 64);                                           \
      if (lane < 8)                                                           \
        red[(C)][wv]                                                          \
           [4 * (lane & 1) + 2 * ((lane >> 1) & 1) + ((lane >> 2) & 1)] = tt; \
    }                                                                         \
    _Pragma("unroll")                                                         \
    for (int i = 0; i < 8; ++i) acc[(SB) + i] = 0.f;                          \
  } while (0)

__global__ __launch_bounds__(512)
void conv1d_kernel(const float* __restrict__ x,
                   const float* __restrict__ filt,
                   const float* __restrict__ bias,
                   float* __restrict__ out) {
  __shared__ float red[32][8][8];  // 8 KB: [chunk][wave][output-in-chunk]
  const int tid = threadIdx.x;
  const int lane = tid & 63;
  const int wv = tid >> 6;   // 0..7

  // XCD-contiguous swizzle (NBLK % 8 == 0)
  const int bid = blockIdx.x;
  const int lbid = (bid & 7) * (NBLK / 8) + (bid >> 3);
  const int b = lbid >> 4;   // / SPR (=16)
  const int seg = lbid & 15;
  const int seg_start = seg * SEG;
  const bool tail = (seg == SPR - 1);
  // interior: frames phi 0..270 (groups 0..67; group 67 loads phi 271 from
  // the next segment -- in-bounds, unused). tail: phi < 256 -> groups < 64;
  // the rest is the reference's zero padding (skipped = adds zero).
  const int glim = tail ? 64 : 68;

  // filter column d = tid for all 16 taps: 16 VGPR
  float w[16];
#pragma unroll
  for (int k = 0; k < 16; ++k) w[k] = filt[k * D + tid];

  float acc[24];
#pragma unroll
  for (int i = 0; i < 24; ++i) acc[i] = 0.f;

  // lane's element of frame phi lives at pfp0 + phi*D
  const float* pfp = x + ((size_t)b * S + seg_start) * D + tid;

  float pfA[4], pfB[4], pfC[4], pfD[4];  // 4-deep prefetch (buffer = G mod 4)
  PF(pfA, 0);
  PF(pfB, 1);
  PF(pfC, 2);
  PF(pfD, 3);

  // ---- prologue: groups 0..5 (phi 0..23); khi clamped to phi for phi<15 ----
  FRAME(pfA[0], 0, 0, 0); FRAME(pfA[1], 1, 0, 1);
  FRAME(pfA[2], 2, 0, 2); FRAME(pfA[3], 3, 0, 3);
  PF(pfA, 4);
  FRAME(pfB[0], 4, 0, 4); FRAME(pfB[1], 5, 0, 5);
  FRAME(pfB[2], 6, 0, 6); FRAME(pfB[3], 7, 0, 7);
  PF(pfB, 5);
  FRAME(pfC[0], 8, 0, 8); FRAME(pfC[1], 9, 0, 9);
  FRAME(pfC[2], 10, 0, 10); FRAME(pfC[3], 11, 0, 11);
  PF(pfC, 6);
  FRAME(pfD[0], 12, 0, 12); FRAME(pfD[1], 13, 0, 13);
  FRAME(pfD[2], 14, 0, 14); FRAME(pfD[3], 15, 0, 15);
  PF(pfD, 7);
  CONSUME(pfA, 4, 16);
  PF(pfA, 8);
  CONSUME(pfB, 5, 20);
  FOLD(0, 0);
  PF(pfB, 9);

  // ---- rolled main: five 12-group bodies, groups 6..65 ----
  for (int g0 = 6; g0 <= 54; g0 += 12) {
    const int cb = (g0 - 4) / 2;  // fold chunk base: 1,7,13,19,25
    CONSUME(pfC, g0 + 0, 0);
    PF(pfC, g0 + 4);
    CONSUME(pfD, g0 + 1, 4);
    FOLD(8, cb);
    PF(pfD, g0 + 5);
    CONSUME(pfA, g0 + 2, 8);
    PF(pfA, g0 + 6);
    CONSUME(pfB, g0 + 3, 12);
    FOLD(16, cb + 1);
    PF(pfB, g0 + 7);
    CONSUME(pfC, g0 + 4, 16);
    PF(pfC, g0 + 8);
    CONSUME(pfD, g0 + 5, 20);
    FOLD(0, cb + 2);
    PF(pfD, g0 + 9);
    CONSUME(pfA, g0 + 6, 0);
    PF(pfA, g0 + 10);
    CONSUME(pfB, g0 + 7, 4);
    FOLD(8, cb + 3);
    PF(pfB, g0 + 11);
    CONSUME(pfC, g0 + 8, 8);
    PF(pfC, g0 + 12);
    CONSUME(pfD, g0 + 9, 12);
    FOLD(16, cb + 4);
    PF(pfD, g0 + 13);
    CONSUME(pfA, g0 + 10, 16);
    PF(pfA, g0 + 14);
    CONSUME(pfB, g0 + 11, 20);
    FOLD(0, cb + 5);
    PF(pfB, g0 + 15);
  }

  // ---- epilogue: groups 66 (pfC, phi 264..267) and 67 (pfD, phi 268..270);
  //      klo = phi - 255; then fold chunk 31 (outputs 248..255, slot base 8) ----
  if (66 < glim) {
    FRAME(pfC[0], 0, 9, 15);  FRAME(pfC[1], 1, 10, 15);
    FRAME(pfC[2], 2, 11, 15); FRAME(pfC[3], 3, 12, 15);
  }
  if (67 < glim) {
    FRAME(pfD[0], 4, 13, 15); FRAME(pfD[1], 5, 14, 15);
    FRAME(pfD[2], 6, 15, 15);  // phi 271 has no valid taps
  }
  FOLD(8, 31);

  __syncthreads();

  // combine the 8 wave-partials per output + bias; coalesced 1 KB store
  if (tid < SEG) {
    const int c = tid >> 3, o = tid & 7;
    float v = bias[0];
#pragma unroll
    for (int wvi = 0; wvi < 8; ++wvi) v += red[c][wvi][o];
    out[(size_t)b * S + seg_start + tid] = v;
  }
}
}  // namespace

extern "C" void kernel_launch(void* const* d_in, const int* in_sizes, int n_in,
                              void* d_out, int out_size, void* d_ws, size_t ws_size,
                              hipStream_t stream) {
  const float* x = (const float*)d_in[0];
  const float* filt = (const float*)d_in[1];
  const float* bias = (const float*)d_in[2];
  float* out = (float*)d_out;

  hipLaunchKernelGGL(conv1d_kernel, dim3(NBLK), dim3(512), 0, stream,
                     x, filt, bias, out);
}